// Round 3
// baseline (128.795 us; speedup 1.0000x reference)
//
#include <hip/hip_runtime.h>

// Phosphene simulator, MI355X.
// ref: 256 discs (r<=15, centers >=20px from edge), separable 21-tap truncated
// Gaussian blur (sigma=r/3, support +-ceil(2*sigma)<=10) with reflect pad,
// threshold 0.05, sum, clamp 1.0, max-normalize.
// Key fact: each phosphene's nonzero support is <= 51x51 px -> render only the
// patch, atomicAdd into the image. Launch-overhead bound, not roofline bound.

#define SIZE   512
#define NPIX   (SIZE * SIZE)
#define H      10
#define KW     21
#define THRESH 0.05f

__global__ __launch_bounds__(256) void zero_k(float* __restrict__ img,
                                              unsigned* __restrict__ mx)
{
  // 256 blocks x 256 threads x float4 = 262144 floats = NPIX
  int i = blockIdx.x * 256 + threadIdx.x;
  ((float4*)img)[i] = make_float4(0.f, 0.f, 0.f, 0.f);
  if (i == 0) *mx = 0u;
}

__global__ __launch_bounds__(256) void phos_accum(
    const float* __restrict__ pc, const float* __restrict__ grid,
    float* __restrict__ img)
{
  // vertical-blur patch: <=51 rows x <=31 disc cols; stride 32
  __shared__ float vert[51 * 32];

  const int p = blockIdx.x;
  const float x = grid[3 * p + 0];
  const float y = grid[3 * p + 1];
  const float r = grid[3 * p + 2];
  const float b = pc[p];

  // weights: exp(-0.5*(pos/sigma)^2) * (|pos| <= ceil(2*sigma)), normalized.
  const float sigma = r / 3.0f;
  const float halfw = ceilf(2.0f * sigma);
  float w[KW];
  float s = 0.0f;
#pragma unroll
  for (int t = 0; t < KW; ++t) {
    float pos = (float)(t - H);
    float wt = (fabsf(pos) <= halfw)
                   ? expf(-0.5f * (pos / sigma) * (pos / sigma))
                   : 0.0f;
    w[t] = wt;
    s += wt;
  }
#pragma unroll
  for (int t = 0; t < KW; ++t) w[t] /= s;

  // disc bounds in 0-based index space; pixel i has coordinate c = i+1,
  // so disc center is (x-1, y-1).
  const float cx = x - 1.0f;
  const float cy = y - 1.0f;
  int icmin = max((int)ceilf(cx - r), 0);
  int icmax = min((int)floorf(cx + r), SIZE - 1);
  int irmin = max((int)ceilf(cy - r), 0);
  int irmax = min((int)floorf(cy + r), SIZE - 1);
  // output (blurred) patch bounds; blur support is +-H around disc rows/cols.
  const int ox0 = max(0, icmin - H), ox1 = min(SIZE - 1, icmax + H);
  const int oy0 = max(0, irmin - H), oy1 = min(SIZE - 1, irmax + H);
  const int ncol = icmax - icmin + 1;  // <= 31
  const int nrow = oy1 - oy0 + 1;      // <= 51
  const float r2 = r * r;

  // pass 1: vertical blur of analytic disc mask, reflect rows at 0 / 511.
  for (int idx = threadIdx.x; idx < nrow * ncol; idx += blockDim.x) {
    int cj = idx / ncol;
    int ci = idx - cj * ncol;
    int c  = icmin + ci;
    float dx  = (float)c - cx;
    float dx2 = dx * dx;
    int j = oy0 + cj;
    float acc = 0.0f;
#pragma unroll
    for (int t = 0; t < KW; ++t) {
      int jj = j + (t - H);
      jj = (jj < 0) ? -jj : ((jj > SIZE - 1) ? 2 * (SIZE - 1) - jj : jj);
      float dy = (float)jj - cy;
      acc += (dx2 + dy * dy <= r2) ? w[t] : 0.0f;
    }
    vert[cj * 32 + ci] = acc;
  }
  __syncthreads();

  // pass 2: horizontal blur, scale by brightness, threshold, accumulate.
  // Reflect note: the ref vertically blurs the reflect-padded columns too,
  // but vertical blur is column-independent, so vert(reflected col) ==
  // vert(col) — reflecting ii into [0,511] then windowing to disc columns
  // is exact.
  const int nox = ox1 - ox0 + 1;  // <= 51
  for (int idx = threadIdx.x; idx < nrow * nox; idx += blockDim.x) {
    int cj = idx / nox;
    int ci = idx - cj * nox;
    int i = ox0 + ci;
    int j = oy0 + cj;
    float acc = 0.0f;
#pragma unroll
    for (int t = 0; t < KW; ++t) {
      int ii = i + (t - H);
      ii = (ii < 0) ? -ii : ((ii > SIZE - 1) ? 2 * (SIZE - 1) - ii : ii);
      int cc = ii - icmin;
      if ((unsigned)cc < (unsigned)ncol) acc += w[t] * vert[cj * 32 + cc];
    }
    float val = acc * b;
    // ref: where(out < THRESH, 0, out) -> only add kept values (also skips
    // zero-add atomic traffic).
    if (val >= THRESH) atomicAdd(&img[j * SIZE + i], val);
  }
}

__global__ __launch_bounds__(256) void clip_max_k(float* __restrict__ img,
                                                  unsigned* __restrict__ mx)
{
  int i = blockIdx.x * 256 + threadIdx.x;
  float v = fminf(img[i], 1.0f);
  img[i] = v;
  // all values >= 0, so float ordering == uint-bit ordering.
  float m = v;
#pragma unroll
  for (int off = 32; off > 0; off >>= 1)
    m = fmaxf(m, __shfl_down(m, off, 64));
  if ((threadIdx.x & 63) == 0) atomicMax(mx, __float_as_uint(m));
}

__global__ __launch_bounds__(256) void norm_k(float* __restrict__ img,
                                              const unsigned* __restrict__ mx)
{
  int i = blockIdx.x * 256 + threadIdx.x;
  float m = __uint_as_float(*mx);
  float v = img[i];
  img[i] = (m > 0.0f) ? v / m : v;
}

extern "C" void kernel_launch(void* const* d_in, const int* in_sizes, int n_in,
                              void* d_out, int out_size, void* d_ws, size_t ws_size,
                              hipStream_t stream)
{
  const float* pc   = (const float*)d_in[0];  // phoscoding (256,)
  const float* grid = (const float*)d_in[1];  // grid (256,3): x,y,r
  float* img   = (float*)d_out;               // (1,1,512,512) f32
  unsigned* mx = (unsigned*)d_ws;             // 4 bytes: running max bits

  zero_k<<<NPIX / (256 * 4), 256, 0, stream>>>(img, mx);
  phos_accum<<<256, 256, 0, stream>>>(pc, grid, img);
  clip_max_k<<<NPIX / 256, 256, 0, stream>>>(img, mx);
  norm_k<<<NPIX / 256, 256, 0, stream>>>(img, mx);
}

// Round 4
// 82.664 us; speedup vs baseline: 1.5581x; 1.5581x over previous
//
#include <hip/hip_runtime.h>

// Phosphene simulator, MI355X.
// ref: 256 discs (r<=15), separable 21-tap truncated Gaussian (sigma=r/3,
// support +-ceil(2*sigma)<=10, reflect pad), threshold 0.05, sum, clamp 1.0,
// max-normalize. Each phosphene's support <= 51x51 px -> patch rendering.
// R3 lesson: 4096 same-address atomicMax = 48.7us. Now: 64 block-level
// atomics, and clip folded into normalize via max(min(img,1))==min(max,1).

#define SIZE   512
#define NPIX   (SIZE * SIZE)
#define H      10
#define KW     21
#define THRESH 0.05f

__global__ __launch_bounds__(256) void zero_k(float* __restrict__ img,
                                              unsigned* __restrict__ mx)
{
  // 256 blocks x 256 threads x float4 = NPIX floats
  int i = blockIdx.x * 256 + threadIdx.x;
  ((float4*)img)[i] = make_float4(0.f, 0.f, 0.f, 0.f);
  if (i == 0) *mx = 0u;
}

__global__ __launch_bounds__(256) void phos_accum(
    const float* __restrict__ pc, const float* __restrict__ grid,
    float* __restrict__ img)
{
  // vertical-blur patch: <=51 rows x <=31 disc cols; stride 32
  __shared__ float vert[51 * 32];

  const int p = blockIdx.x;
  const float x = grid[3 * p + 0];
  const float y = grid[3 * p + 1];
  const float r = grid[3 * p + 2];
  const float b = pc[p];

  // weights: exp(-0.5*(pos/sigma)^2) * (|pos| <= ceil(2*sigma)), normalized.
  const float sigma = r / 3.0f;
  const float halfw = ceilf(2.0f * sigma);
  float w[KW];
  float s = 0.0f;
#pragma unroll
  for (int t = 0; t < KW; ++t) {
    float pos = (float)(t - H);
    float wt = (fabsf(pos) <= halfw)
                   ? expf(-0.5f * (pos / sigma) * (pos / sigma))
                   : 0.0f;
    w[t] = wt;
    s += wt;
  }
#pragma unroll
  for (int t = 0; t < KW; ++t) w[t] /= s;

  // pixel i has coordinate c = i+1, so disc center is (x-1, y-1) 0-based.
  const float cx = x - 1.0f;
  const float cy = y - 1.0f;
  int icmin = max((int)ceilf(cx - r), 0);
  int icmax = min((int)floorf(cx + r), SIZE - 1);
  int irmin = max((int)ceilf(cy - r), 0);
  int irmax = min((int)floorf(cy + r), SIZE - 1);
  const int ox0 = max(0, icmin - H), ox1 = min(SIZE - 1, icmax + H);
  const int oy0 = max(0, irmin - H), oy1 = min(SIZE - 1, irmax + H);
  const int ncol = icmax - icmin + 1;  // <= 31
  const int nrow = oy1 - oy0 + 1;      // <= 51
  const float r2 = r * r;

  // pass 1: vertical blur of analytic disc mask, reflect rows at 0 / 511.
  for (int idx = threadIdx.x; idx < nrow * ncol; idx += blockDim.x) {
    int cj = idx / ncol;
    int ci = idx - cj * ncol;
    int c  = icmin + ci;
    float dx  = (float)c - cx;
    float dx2 = dx * dx;
    int j = oy0 + cj;
    float acc = 0.0f;
#pragma unroll
    for (int t = 0; t < KW; ++t) {
      int jj = j + (t - H);
      jj = (jj < 0) ? -jj : ((jj > SIZE - 1) ? 2 * (SIZE - 1) - jj : jj);
      float dy = (float)jj - cy;
      acc += (dx2 + dy * dy <= r2) ? w[t] : 0.0f;
    }
    vert[cj * 32 + ci] = acc;
  }
  __syncthreads();

  // pass 2: horizontal blur (reflect cols), scale, threshold, accumulate.
  // vert(reflected col) == vert(col) since vertical blur is col-independent.
  const int nox = ox1 - ox0 + 1;  // <= 51
  for (int idx = threadIdx.x; idx < nrow * nox; idx += blockDim.x) {
    int cj = idx / nox;
    int ci = idx - cj * nox;
    int i = ox0 + ci;
    int j = oy0 + cj;
    float acc = 0.0f;
#pragma unroll
    for (int t = 0; t < KW; ++t) {
      int ii = i + (t - H);
      ii = (ii < 0) ? -ii : ((ii > SIZE - 1) ? 2 * (SIZE - 1) - ii : ii);
      int cc = ii - icmin;
      if ((unsigned)cc < (unsigned)ncol) acc += w[t] * vert[cj * 32 + cc];
    }
    float val = acc * b;
    if (val >= THRESH) atomicAdd(&img[j * SIZE + i], val);
  }
}

// Max over RAW sums (read-only). max(min(img,1)) == min(max_raw,1) since
// clamp is monotone — clip pass eliminated. 64 blocks -> 64 atomics total.
__global__ __launch_bounds__(256) void max_k(const float* __restrict__ img,
                                             unsigned* __restrict__ mx)
{
  __shared__ float smax[4];
  const float4* im4 = (const float4*)img;
  float m = 0.0f;
  for (int i = blockIdx.x * 256 + threadIdx.x; i < NPIX / 4;
       i += gridDim.x * 256) {
    float4 v = im4[i];
    m = fmaxf(m, fmaxf(fmaxf(v.x, v.y), fmaxf(v.z, v.w)));
  }
#pragma unroll
  for (int off = 32; off > 0; off >>= 1)
    m = fmaxf(m, __shfl_down(m, off, 64));
  if ((threadIdx.x & 63) == 0) smax[threadIdx.x >> 6] = m;
  __syncthreads();
  if (threadIdx.x == 0) {
    m = fmaxf(fmaxf(smax[0], smax[1]), fmaxf(smax[2], smax[3]));
    // all values >= 0 -> float ordering == uint-bit ordering.
    atomicMax(mx, __float_as_uint(m));
  }
}

// Fused clip + normalize: out = min(v,1) / min(max_raw,1)  (if max>0).
__global__ __launch_bounds__(256) void norm_clip_k(
    float* __restrict__ img, const unsigned* __restrict__ mx)
{
  int i = blockIdx.x * 256 + threadIdx.x;
  float m = fminf(__uint_as_float(*mx), 1.0f);
  float4 v = ((float4*)img)[i];
  v.x = fminf(v.x, 1.0f);
  v.y = fminf(v.y, 1.0f);
  v.z = fminf(v.z, 1.0f);
  v.w = fminf(v.w, 1.0f);
  if (m > 0.0f) {
    v.x /= m; v.y /= m; v.z /= m; v.w /= m;
  }
  ((float4*)img)[i] = v;
}

extern "C" void kernel_launch(void* const* d_in, const int* in_sizes, int n_in,
                              void* d_out, int out_size, void* d_ws, size_t ws_size,
                              hipStream_t stream)
{
  const float* pc   = (const float*)d_in[0];  // phoscoding (256,)
  const float* grid = (const float*)d_in[1];  // grid (256,3): x,y,r
  float* img   = (float*)d_out;               // (1,1,512,512) f32
  unsigned* mx = (unsigned*)d_ws;             // 4 bytes: raw-max bits

  zero_k<<<NPIX / (256 * 4), 256, 0, stream>>>(img, mx);
  phos_accum<<<256, 256, 0, stream>>>(pc, grid, img);
  max_k<<<64, 256, 0, stream>>>(img, mx);
  norm_clip_k<<<NPIX / (256 * 4), 256, 0, stream>>>(img, mx);
}